// Round 1
// baseline (1475.302 us; speedup 1.0000x reference)
//
#include <hip/hip_runtime.h>

#define NN 100000
#define NE 3200000

// ---------------- degree count ----------------
__global__ __launch_bounds__(256) void count_kernel(const int* __restrict__ dst,
                                                    int* __restrict__ cnt, int E) {
  int i = blockIdx.x * 256 + threadIdx.x;
  if (i < E) atomicAdd(&cnt[dst[i]], 1);
}

__global__ __launch_bounds__(256) void dinv_kernel(const int* __restrict__ cnt,
                                                   float* __restrict__ dinv, int n) {
  int i = blockIdx.x * 256 + threadIdx.x;
  if (i < n) dinv[i] = rsqrtf((float)(cnt[i] + 1));  // +1 self-loop
}

// ---------------- exclusive scan (single block) ----------------
__global__ __launch_bounds__(1024) void scan_kernel(const int* __restrict__ cnt,
                                                    int* __restrict__ row_ptr, int n) {
  __shared__ int sums[1024];
  int tid = threadIdx.x;
  int chunk = (n + 1023) / 1024;
  int start = tid * chunk;
  int end = min(start + chunk, n);
  int s = 0;
  for (int i = start; i < end; ++i) s += cnt[i];
  sums[tid] = s;
  __syncthreads();
  for (int off = 1; off < 1024; off <<= 1) {
    int v = (tid >= off) ? sums[tid - off] : 0;
    __syncthreads();
    sums[tid] += v;
    __syncthreads();
  }
  int run = (tid > 0) ? sums[tid - 1] : 0;
  for (int i = start; i < end; ++i) { row_ptr[i] = run; run += cnt[i]; }
  if (end == n) row_ptr[n] = run;
}

// ---------------- CSR fill ----------------
__global__ __launch_bounds__(256) void fill_kernel(const int* __restrict__ src,
                                                   const int* __restrict__ dst,
                                                   const int* __restrict__ row_ptr,
                                                   int* __restrict__ cursor,
                                                   int* __restrict__ csr_src, int E) {
  int i = blockIdx.x * 256 + threadIdx.x;
  if (i < E) {
    int d = dst[i];
    int pos = row_ptr[d] + atomicAdd(&cursor[d], 1);
    csr_src[pos] = src[i];
  }
}

// ---------------- fp32 GEMM: C[M][BN] = X[M][128] @ W[128][BN] ----------------
template <int BN>
__global__ __launch_bounds__(512) void gemm_kernel(const float* __restrict__ X,
                                                   const float* __restrict__ W,
                                                   float* __restrict__ C, int M) {
  constexpr int BM = 128, K = 128;
  constexpr int RPT = BN / 16;        // rows per thread (8 or 4)
  constexpr int TX = BN / 4;          // col-thread count (32 or 16)
  __shared__ float Xs[BM][K + 4];
  __shared__ float Ws[K][BN];
  int tid = threadIdx.x;
  int row0 = blockIdx.x * BM;

  // stage W (whole matrix)
  for (int idx = tid * 4; idx < K * BN; idx += 512 * 4)
    *(float4*)&(((float*)Ws)[idx]) = *(const float4*)&W[idx];
  // stage X tile
  for (int idx = tid * 4; idx < BM * K; idx += 512 * 4) {
    int r = idx / K, c = idx % K;
    float4 v = make_float4(0.f, 0.f, 0.f, 0.f);
    if (row0 + r < M) v = *(const float4*)&X[(size_t)(row0 + r) * K + c];
    *(float4*)&Xs[r][c] = v;
  }
  __syncthreads();

  int tx = tid % TX, ty = tid / TX;
  float acc[RPT][4];
#pragma unroll
  for (int i = 0; i < RPT; ++i)
#pragma unroll
    for (int j = 0; j < 4; ++j) acc[i][j] = 0.f;

  for (int k = 0; k < K; k += 4) {
    float bv[4][4];
#pragma unroll
    for (int kk = 0; kk < 4; ++kk) {
      float4 b = *(float4*)&Ws[k + kk][tx * 4];
      bv[kk][0] = b.x; bv[kk][1] = b.y; bv[kk][2] = b.z; bv[kk][3] = b.w;
    }
#pragma unroll
    for (int i = 0; i < RPT; ++i) {
      float4 a = *(float4*)&Xs[ty * RPT + i][k];
      float av[4] = {a.x, a.y, a.z, a.w};
#pragma unroll
      for (int kk = 0; kk < 4; ++kk)
#pragma unroll
        for (int j = 0; j < 4; ++j)
          acc[i][j] = fmaf(av[kk], bv[kk][j], acc[i][j]);
    }
  }

#pragma unroll
  for (int i = 0; i < RPT; ++i) {
    int row = row0 + ty * RPT + i;
    if (row < M) {
      float4 st = make_float4(acc[i][0], acc[i][1], acc[i][2], acc[i][3]);
      *(float4*)&C[(size_t)row * BN + tx * 4] = st;
    }
  }
}

// ---------------- aggregation: H[n] = sum_{e: dst=n} norm * T[src] + dinv^2*T[n] + b ----------------
// LPN lanes per node, 2 channels per lane (C = 2*LPN)
template <int LPN, bool RELU, bool FUSE_OUT>
__global__ __launch_bounds__(256) void agg_kernel(const float* __restrict__ T,
                                                  const int* __restrict__ row_ptr,
                                                  const int* __restrict__ csr_src,
                                                  const float* __restrict__ dinv,
                                                  const float* __restrict__ bias,
                                                  float* __restrict__ H,
                                                  const float* __restrict__ Wout,
                                                  const float* __restrict__ bout,
                                                  float* __restrict__ Out, int n) {
  int t = blockIdx.x * 256 + threadIdx.x;
  int node = t / LPN;
  int lane = t % LPN;
  if (node >= n) return;

  float dn = dinv[node];
  const float2* Trow = (const float2*)T;
  float2 acc = Trow[(size_t)node * LPN + lane];
  float w0 = dn * dn;  // self-loop norm
  acc.x *= w0; acc.y *= w0;

  int beg = row_ptr[node], end = row_ptr[node + 1];
  for (int e = beg; e < end; ++e) {
    int s = csr_src[e];
    float w = dinv[s] * dn;
    float2 v = Trow[(size_t)s * LPN + lane];
    acc.x = fmaf(v.x, w, acc.x);
    acc.y = fmaf(v.y, w, acc.y);
  }
  acc.x += bias[2 * lane];
  acc.y += bias[2 * lane + 1];
  if (RELU) { acc.x = fmaxf(acc.x, 0.f); acc.y = fmaxf(acc.y, 0.f); }
  ((float2*)H)[(size_t)node * LPN + lane] = acc;

  if (FUSE_OUT) {  // C==64, LPN==32: out[n][o] = sum_k h[k]*Wout[k][o] + bout[o]
    float p0 = acc.x * Wout[(2 * lane) * 2 + 0] + acc.y * Wout[(2 * lane + 1) * 2 + 0];
    float p1 = acc.x * Wout[(2 * lane) * 2 + 1] + acc.y * Wout[(2 * lane + 1) * 2 + 1];
#pragma unroll
    for (int off = 16; off >= 1; off >>= 1) {
      p0 += __shfl_xor(p0, off, 32);
      p1 += __shfl_xor(p1, off, 32);
    }
    if (lane == 0) {
      Out[(size_t)node * 2 + 0] = p0 + bout[0];
      Out[(size_t)node * 2 + 1] = p1 + bout[1];
    }
  }
}

extern "C" void kernel_launch(void* const* d_in, const int* in_sizes, int n_in,
                              void* d_out, int out_size, void* d_ws, size_t ws_size,
                              hipStream_t stream) {
  const float* x    = (const float*)d_in[0];
  const int*   ei   = (const int*)d_in[1];
  const float* W1   = (const float*)d_in[2];
  const float* b1   = (const float*)d_in[3];
  const float* W2   = (const float*)d_in[4];
  const float* b2   = (const float*)d_in[5];
  const float* W3   = (const float*)d_in[6];
  const float* b3   = (const float*)d_in[7];
  const float* Wout = (const float*)d_in[8];
  const float* bout = (const float*)d_in[9];

  const int n = NN, E = NE;
  const int* srcp = ei;
  const int* dstp = ei + E;

  char* ws = (char*)d_ws;
  int*   cnt     = (int*)(ws + 0);          // 400000 B
  int*   cursor  = (int*)(ws + 400000);     // 400000 B
  int*   row_ptr = (int*)(ws + 800000);     // 400004 B (n+1)
  float* dinv    = (float*)(ws + 1200128);  // 400000 B
  int*   csr_src = (int*)(ws + 1600128);    // 12.8 MB
  float* bufA    = (float*)(ws + 14400128); // 51.2 MB
  float* bufB    = (float*)(ws + 65600128); // 51.2 MB (total ~111.4 MB)

  float* outp = (float*)d_out;        // [n,2]
  float* hemb = (float*)d_out + 2 * n;  // [n,64]

  hipMemsetAsync(cnt, 0, n * sizeof(int), stream);
  hipMemsetAsync(cursor, 0, n * sizeof(int), stream);

  count_kernel<<<(E + 255) / 256, 256, 0, stream>>>(dstp, cnt, E);
  dinv_kernel<<<(n + 255) / 256, 256, 0, stream>>>(cnt, dinv, n);
  scan_kernel<<<1, 1024, 0, stream>>>(cnt, row_ptr, n);
  fill_kernel<<<(E + 255) / 256, 256, 0, stream>>>(srcp, dstp, row_ptr, cursor, csr_src, E);

  // layer 1: t = x @ W1 ; h1 = relu(agg(t) + b1)
  gemm_kernel<128><<<(n + 127) / 128, 512, 0, stream>>>(x, W1, bufA, n);
  agg_kernel<64, true, false><<<(n * 64 + 255) / 256, 256, 0, stream>>>(
      bufA, row_ptr, csr_src, dinv, b1, bufB, nullptr, nullptr, nullptr, n);

  // layer 2
  gemm_kernel<128><<<(n + 127) / 128, 512, 0, stream>>>(bufB, W2, bufA, n);
  agg_kernel<64, true, false><<<(n * 64 + 255) / 256, 256, 0, stream>>>(
      bufA, row_ptr, csr_src, dinv, b2, bufB, nullptr, nullptr, nullptr, n);

  // layer 3 (embedding, no relu) + fused final linear
  gemm_kernel<64><<<(n + 127) / 128, 512, 0, stream>>>(bufB, W3, bufA, n);
  agg_kernel<32, false, true><<<(n * 32 + 255) / 256, 256, 0, stream>>>(
      bufA, row_ptr, csr_src, dinv, b3, hemb, Wout, bout, outp, n);
}

// Round 2
// 1198.159 us; speedup vs baseline: 1.2313x; 1.2313x over previous
//
#include <hip/hip_runtime.h>

#define NN 100000
#define NE 3200000

// ---------------- degree count ----------------
__global__ __launch_bounds__(256) void count_kernel(const int* __restrict__ dst,
                                                    int* __restrict__ cnt, int E) {
  int i = blockIdx.x * 256 + threadIdx.x;
  if (i < E) atomicAdd(&cnt[dst[i]], 1);
}

__global__ __launch_bounds__(256) void dinv_kernel(const int* __restrict__ cnt,
                                                   float* __restrict__ dinv, int n) {
  int i = blockIdx.x * 256 + threadIdx.x;
  if (i < n) dinv[i] = rsqrtf((float)(cnt[i] + 1));  // +1 self-loop
}

// ---------------- exclusive scan (single block) ----------------
__global__ __launch_bounds__(1024) void scan_kernel(const int* __restrict__ cnt,
                                                    int* __restrict__ row_ptr, int n) {
  __shared__ int sums[1024];
  int tid = threadIdx.x;
  int chunk = (n + 1023) / 1024;
  int start = tid * chunk;
  int end = min(start + chunk, n);
  int s = 0;
  for (int i = start; i < end; ++i) s += cnt[i];
  sums[tid] = s;
  __syncthreads();
  for (int off = 1; off < 1024; off <<= 1) {
    int v = (tid >= off) ? sums[tid - off] : 0;
    __syncthreads();
    sums[tid] += v;
    __syncthreads();
  }
  int run = (tid > 0) ? sums[tid - 1] : 0;
  for (int i = start; i < end; ++i) { row_ptr[i] = run; run += cnt[i]; }
  if (end == n) row_ptr[n] = run;
}

// ---------------- CSR fill ----------------
__global__ __launch_bounds__(256) void fill_kernel(const int* __restrict__ src,
                                                   const int* __restrict__ dst,
                                                   const int* __restrict__ row_ptr,
                                                   int* __restrict__ cursor,
                                                   int* __restrict__ csr_src, int E) {
  int i = blockIdx.x * 256 + threadIdx.x;
  if (i < E) {
    int d = dst[i];
    int pos = row_ptr[d] + atomicAdd(&cursor[d], 1);
    csr_src[pos] = src[i];
  }
}

// ---------------- fp32 GEMM: C[M][N] = (X[M][128] @ W[128][N]) * dinv[row] ----------------
// BM=128, BN=64 (gridDim.y tiles N), BK=32, 512 threads, ~25KB LDS.
template <int N>
__global__ __launch_bounds__(512) void gemm_kernel(const float* __restrict__ X,
                                                   const float* __restrict__ W,
                                                   const float* __restrict__ dinv,
                                                   float* __restrict__ C, int M) {
  constexpr int BM = 128, BN = 64, BK = 32, K = 128;
  __shared__ float XsT[BK][BM + 4];  // transposed; row stride 132 floats (16B-mult)
  __shared__ float Ws[BK][BN];
  int tid = threadIdx.x;
  int row0 = blockIdx.x * BM;
  int col0 = blockIdx.y * BN;
  int tx = tid & 15;   // 16 col groups * 4
  int ty = tid >> 4;   // 32 row groups * 4

  float acc[4][4];
#pragma unroll
  for (int i = 0; i < 4; ++i)
#pragma unroll
    for (int j = 0; j < 4; ++j) acc[i][j] = 0.f;

  for (int k0 = 0; k0 < K; k0 += BK) {
    // stage W tile: 32x64 = 512 float4s, one per thread
    {
      int r = tid >> 4;           // 0..31
      int c4 = (tid & 15) * 4;    // 0..60
      *(float4*)&Ws[r][c4] = *(const float4*)&W[(size_t)(k0 + r) * N + col0 + c4];
    }
    // stage X^T: 128x32 = 1024 float4-loads worth, 2 per thread, scatter-transpose
#pragma unroll
    for (int i = 0; i < 2; ++i) {
      int idx = tid + i * 512;    // 0..1023
      int r = idx >> 3;           // 0..127
      int c = (idx & 7) * 4;      // 0..28
      float4 v = make_float4(0.f, 0.f, 0.f, 0.f);
      if (row0 + r < M) v = *(const float4*)&X[(size_t)(row0 + r) * K + k0 + c];
      XsT[c + 0][r] = v.x;
      XsT[c + 1][r] = v.y;
      XsT[c + 2][r] = v.z;
      XsT[c + 3][r] = v.w;
    }
    __syncthreads();

#pragma unroll
    for (int kk = 0; kk < BK; ++kk) {
      float4 a = *(float4*)&XsT[kk][ty * 4];
      float4 b = *(float4*)&Ws[kk][tx * 4];
      float av[4] = {a.x, a.y, a.z, a.w};
      float bv[4] = {b.x, b.y, b.z, b.w};
#pragma unroll
      for (int i = 0; i < 4; ++i)
#pragma unroll
        for (int j = 0; j < 4; ++j) acc[i][j] = fmaf(av[i], bv[j], acc[i][j]);
    }
    __syncthreads();
  }

#pragma unroll
  for (int i = 0; i < 4; ++i) {
    int row = row0 + ty * 4 + i;
    if (row < M) {
      float s = dinv[row];
      float4 st = make_float4(acc[i][0] * s, acc[i][1] * s, acc[i][2] * s, acc[i][3] * s);
      *(float4*)&C[(size_t)row * N + col0 + tx * 4] = st;
    }
  }
}

// ---------------- aggregation over prescaled features ----------------
// Tp[i] = dinv[i] * (X@W)[i].  H[node] = dn * (Tp[node] + sum_src Tp[src]) + b
// LPN lanes per node, 4 channels per lane (C = 4*LPN). Unroll-4 independent accumulators.
template <int LPN, bool RELU, bool FUSE_OUT>
__global__ __launch_bounds__(256) void agg_kernel(const float* __restrict__ Tp,
                                                  const int* __restrict__ row_ptr,
                                                  const int* __restrict__ csr_src,
                                                  const float* __restrict__ dinv,
                                                  const float* __restrict__ bias,
                                                  float* __restrict__ H,
                                                  const float* __restrict__ Wout,
                                                  const float* __restrict__ bout,
                                                  float* __restrict__ Out, int n) {
  int t = blockIdx.x * 256 + threadIdx.x;
  int node = t / LPN;
  int lane = t % LPN;
  if (node >= n) return;

  const float4* Trow = (const float4*)Tp;
  float dn = dinv[node];

  float4 a0 = Trow[(size_t)node * LPN + lane];  // self term (prescaled)
  float4 a1 = make_float4(0.f, 0.f, 0.f, 0.f);
  float4 a2 = a1, a3 = a1;

  int beg = row_ptr[node], end = row_ptr[node + 1];
  int e = beg;
  for (; e + 4 <= end; e += 4) {
    int s0 = csr_src[e + 0];
    int s1 = csr_src[e + 1];
    int s2 = csr_src[e + 2];
    int s3 = csr_src[e + 3];
    float4 v0 = Trow[(size_t)s0 * LPN + lane];
    float4 v1 = Trow[(size_t)s1 * LPN + lane];
    float4 v2 = Trow[(size_t)s2 * LPN + lane];
    float4 v3 = Trow[(size_t)s3 * LPN + lane];
    a0.x += v0.x; a0.y += v0.y; a0.z += v0.z; a0.w += v0.w;
    a1.x += v1.x; a1.y += v1.y; a1.z += v1.z; a1.w += v1.w;
    a2.x += v2.x; a2.y += v2.y; a2.z += v2.z; a2.w += v2.w;
    a3.x += v3.x; a3.y += v3.y; a3.z += v3.z; a3.w += v3.w;
  }
  for (; e < end; ++e) {
    float4 v = Trow[(size_t)csr_src[e] * LPN + lane];
    a0.x += v.x; a0.y += v.y; a0.z += v.z; a0.w += v.w;
  }
  float4 s;
  s.x = (a0.x + a1.x) + (a2.x + a3.x);
  s.y = (a0.y + a1.y) + (a2.y + a3.y);
  s.z = (a0.z + a1.z) + (a2.z + a3.z);
  s.w = (a0.w + a1.w) + (a2.w + a3.w);

  float4 bv = *(const float4*)&bias[4 * lane];
  float4 h;
  h.x = fmaf(dn, s.x, bv.x);
  h.y = fmaf(dn, s.y, bv.y);
  h.z = fmaf(dn, s.z, bv.z);
  h.w = fmaf(dn, s.w, bv.w);
  if (RELU) {
    h.x = fmaxf(h.x, 0.f); h.y = fmaxf(h.y, 0.f);
    h.z = fmaxf(h.z, 0.f); h.w = fmaxf(h.w, 0.f);
  }
  ((float4*)H)[(size_t)node * LPN + lane] = h;

  if (FUSE_OUT) {  // C==64, LPN==16: out[n][o] = sum_k h[k]*Wout[k][o] + bout[o]
    int k0 = 4 * lane;
    float p0 = h.x * Wout[(k0 + 0) * 2 + 0] + h.y * Wout[(k0 + 1) * 2 + 0] +
               h.z * Wout[(k0 + 2) * 2 + 0] + h.w * Wout[(k0 + 3) * 2 + 0];
    float p1 = h.x * Wout[(k0 + 0) * 2 + 1] + h.y * Wout[(k0 + 1) * 2 + 1] +
               h.z * Wout[(k0 + 2) * 2 + 1] + h.w * Wout[(k0 + 3) * 2 + 1];
#pragma unroll
    for (int off = 8; off >= 1; off >>= 1) {
      p0 += __shfl_xor(p0, off, 16);
      p1 += __shfl_xor(p1, off, 16);
    }
    if (lane == 0) {
      Out[(size_t)node * 2 + 0] = p0 + bout[0];
      Out[(size_t)node * 2 + 1] = p1 + bout[1];
    }
  }
}

extern "C" void kernel_launch(void* const* d_in, const int* in_sizes, int n_in,
                              void* d_out, int out_size, void* d_ws, size_t ws_size,
                              hipStream_t stream) {
  const float* x    = (const float*)d_in[0];
  const int*   ei   = (const int*)d_in[1];
  const float* W1   = (const float*)d_in[2];
  const float* b1   = (const float*)d_in[3];
  const float* W2   = (const float*)d_in[4];
  const float* b2   = (const float*)d_in[5];
  const float* W3   = (const float*)d_in[6];
  const float* b3   = (const float*)d_in[7];
  const float* Wout = (const float*)d_in[8];
  const float* bout = (const float*)d_in[9];

  const int n = NN, E = NE;
  const int* srcp = ei;
  const int* dstp = ei + E;

  char* ws = (char*)d_ws;
  int*   cnt     = (int*)(ws + 0);          // 400000 B
  int*   cursor  = (int*)(ws + 400000);     // 400000 B
  int*   row_ptr = (int*)(ws + 800000);     // 400004 B (n+1)
  float* dinv    = (float*)(ws + 1200128);  // 400000 B
  int*   csr_src = (int*)(ws + 1600128);    // 12.8 MB
  float* bufA    = (float*)(ws + 14400128); // 51.2 MB
  float* bufB    = (float*)(ws + 65600128); // 51.2 MB (total ~111.4 MB)

  float* outp = (float*)d_out;          // [n,2]
  float* hemb = (float*)d_out + 2 * n;  // [n,64]

  hipMemsetAsync(cnt, 0, n * sizeof(int), stream);
  hipMemsetAsync(cursor, 0, n * sizeof(int), stream);

  count_kernel<<<(E + 255) / 256, 256, 0, stream>>>(dstp, cnt, E);
  dinv_kernel<<<(n + 255) / 256, 256, 0, stream>>>(cnt, dinv, n);
  scan_kernel<<<1, 1024, 0, stream>>>(cnt, row_ptr, n);
  fill_kernel<<<(E + 255) / 256, 256, 0, stream>>>(srcp, dstp, row_ptr, cursor, csr_src, E);

  // layer 1: Tp = (x @ W1) * dinv ; h1 = relu(dn * (sum) + b1)
  gemm_kernel<128><<<dim3((n + 127) / 128, 2), 512, 0, stream>>>(x, W1, dinv, bufA, n);
  agg_kernel<32, true, false><<<(n * 32 + 255) / 256, 256, 0, stream>>>(
      bufA, row_ptr, csr_src, dinv, b1, bufB, nullptr, nullptr, nullptr, n);

  // layer 2
  gemm_kernel<128><<<dim3((n + 127) / 128, 2), 512, 0, stream>>>(bufB, W2, dinv, bufA, n);
  agg_kernel<32, true, false><<<(n * 32 + 255) / 256, 256, 0, stream>>>(
      bufA, row_ptr, csr_src, dinv, b2, bufB, nullptr, nullptr, nullptr, n);

  // layer 3 (embedding, no relu) + fused final linear
  gemm_kernel<64><<<dim3((n + 127) / 128, 1), 512, 0, stream>>>(bufB, W3, dinv, bufA, n);
  agg_kernel<16, false, true><<<(n * 16 + 255) / 256, 256, 0, stream>>>(
      bufA, row_ptr, csr_src, dinv, b3, hemb, Wout, bout, outp, n);
}

// Round 3
// 1130.876 us; speedup vs baseline: 1.3046x; 1.0595x over previous
//
#include <hip/hip_runtime.h>

#define NN 100000
#define NE 3200000

// ---------------- degree count ----------------
__global__ __launch_bounds__(256) void count_kernel(const int* __restrict__ dst,
                                                    int* __restrict__ cnt, int E) {
  int i = blockIdx.x * 256 + threadIdx.x;
  if (i < E) atomicAdd(&cnt[dst[i]], 1);
}

__global__ __launch_bounds__(256) void dinv_kernel(const int* __restrict__ cnt,
                                                   float* __restrict__ dinv, int n) {
  int i = blockIdx.x * 256 + threadIdx.x;
  if (i < n) dinv[i] = rsqrtf((float)(cnt[i] + 1));  // +1 self-loop
}

// ---------------- exclusive scan (single block, vectorized first pass) ----------------
__global__ __launch_bounds__(1024) void scan_kernel(const int* __restrict__ cnt,
                                                    int* __restrict__ row_ptr, int n) {
  __shared__ int sums[1024];
  int tid = threadIdx.x;
  const int chunk = 100;  // 1024*100 >= NN; multiple of 4 for int4 loads
  int start = tid * chunk;
  int end = min(start + chunk, n);
  int s = 0;
  for (int i = start; i + 4 <= end; i += 4) {
    int4 v = *(const int4*)&cnt[i];
    s += v.x + v.y + v.z + v.w;
  }
  sums[tid] = s;
  __syncthreads();
  for (int off = 1; off < 1024; off <<= 1) {
    int v = (tid >= off) ? sums[tid - off] : 0;
    __syncthreads();
    sums[tid] += v;
    __syncthreads();
  }
  int run = (tid > 0) ? sums[tid - 1] : 0;
  for (int i = start; i < end; ++i) { row_ptr[i] = run; run += cnt[i]; }
  if (end == n && start < n) row_ptr[n] = run;
}

// ---------------- CSR fill ----------------
__global__ __launch_bounds__(256) void fill_kernel(const int* __restrict__ src,
                                                   const int* __restrict__ dst,
                                                   const int* __restrict__ row_ptr,
                                                   int* __restrict__ cursor,
                                                   int* __restrict__ csr_src, int E) {
  int i = blockIdx.x * 256 + threadIdx.x;
  if (i < E) {
    int d = dst[i];
    int pos = row_ptr[d] + atomicAdd(&cursor[d], 1);
    csr_src[pos] = src[i];
  }
}

// ---------------- fp32 GEMM: C[M][N] = (X[M][128] @ W[128][N]) * dinv[row] ----------------
template <int N>
__global__ __launch_bounds__(512) void gemm_kernel(const float* __restrict__ X,
                                                   const float* __restrict__ W,
                                                   const float* __restrict__ dinv,
                                                   float* __restrict__ C, int M) {
  constexpr int BM = 128, BN = 64, BK = 32, K = 128;
  __shared__ float XsT[BK][BM + 4];
  __shared__ float Ws[BK][BN];
  int tid = threadIdx.x;
  int row0 = blockIdx.x * BM;
  int col0 = blockIdx.y * BN;
  int tx = tid & 15;
  int ty = tid >> 4;

  float acc[4][4];
#pragma unroll
  for (int i = 0; i < 4; ++i)
#pragma unroll
    for (int j = 0; j < 4; ++j) acc[i][j] = 0.f;

  for (int k0 = 0; k0 < K; k0 += BK) {
    {
      int r = tid >> 4;
      int c4 = (tid & 15) * 4;
      *(float4*)&Ws[r][c4] = *(const float4*)&W[(size_t)(k0 + r) * N + col0 + c4];
    }
#pragma unroll
    for (int i = 0; i < 2; ++i) {
      int idx = tid + i * 512;
      int r = idx >> 3;
      int c = (idx & 7) * 4;
      float4 v = make_float4(0.f, 0.f, 0.f, 0.f);
      if (row0 + r < M) v = *(const float4*)&X[(size_t)(row0 + r) * K + k0 + c];
      XsT[c + 0][r] = v.x;
      XsT[c + 1][r] = v.y;
      XsT[c + 2][r] = v.z;
      XsT[c + 3][r] = v.w;
    }
    __syncthreads();

#pragma unroll
    for (int kk = 0; kk < BK; ++kk) {
      float4 a = *(float4*)&XsT[kk][ty * 4];
      float4 b = *(float4*)&Ws[kk][tx * 4];
      float av[4] = {a.x, a.y, a.z, a.w};
      float bv[4] = {b.x, b.y, b.z, b.w};
#pragma unroll
      for (int i = 0; i < 4; ++i)
#pragma unroll
        for (int j = 0; j < 4; ++j) acc[i][j] = fmaf(av[i], bv[j], acc[i][j]);
    }
    __syncthreads();
  }

#pragma unroll
  for (int i = 0; i < 4; ++i) {
    int row = row0 + ty * 4 + i;
    if (row < M) {
      float s = dinv[row];
      float4 st = make_float4(acc[i][0] * s, acc[i][1] * s, acc[i][2] * s, acc[i][3] * s);
      *(float4*)&C[(size_t)row * N + col0 + tx * 4] = st;
    }
  }
}

// ---------------- aggregation over prescaled features ----------------
// Tp[i] = dinv[i] * (X@W)[i].  H[node] = dn * (Tp[node] + sum_src Tp[src]) + b
// LPN lanes per node, 4 channels per lane. Unroll-8, int4 index loads.
template <int LPN, bool RELU, bool FUSE_OUT>
__global__ __launch_bounds__(256) void agg_kernel(const float* __restrict__ Tp,
                                                  const int* __restrict__ row_ptr,
                                                  const int* __restrict__ csr_src,
                                                  const float* __restrict__ dinv,
                                                  const float* __restrict__ bias,
                                                  float* __restrict__ H,
                                                  const float* __restrict__ Wout,
                                                  const float* __restrict__ bout,
                                                  float* __restrict__ Out, int n) {
  int t = blockIdx.x * 256 + threadIdx.x;
  int node = t / LPN;
  int lane = t % LPN;
  if (node >= n) return;

  const float4* Trow = (const float4*)Tp;
  float dn = dinv[node];

  float4 acc[8];
  acc[0] = Trow[(size_t)node * LPN + lane];  // self term (prescaled)
#pragma unroll
  for (int i = 1; i < 8; ++i) acc[i] = make_float4(0.f, 0.f, 0.f, 0.f);

  int beg = row_ptr[node], end = row_ptr[node + 1];
  int e = beg;
  // align e to 4 for int4 index loads
  int ae = min(end, (beg + 3) & ~3);
  for (; e < ae; ++e) {
    float4 v = Trow[(size_t)csr_src[e] * LPN + lane];
    acc[0].x += v.x; acc[0].y += v.y; acc[0].z += v.z; acc[0].w += v.w;
  }
  for (; e + 8 <= end; e += 8) {
    int4 ia = *(const int4*)&csr_src[e];
    int4 ib = *(const int4*)&csr_src[e + 4];
    float4 v0 = Trow[(size_t)ia.x * LPN + lane];
    float4 v1 = Trow[(size_t)ia.y * LPN + lane];
    float4 v2 = Trow[(size_t)ia.z * LPN + lane];
    float4 v3 = Trow[(size_t)ia.w * LPN + lane];
    float4 v4 = Trow[(size_t)ib.x * LPN + lane];
    float4 v5 = Trow[(size_t)ib.y * LPN + lane];
    float4 v6 = Trow[(size_t)ib.z * LPN + lane];
    float4 v7 = Trow[(size_t)ib.w * LPN + lane];
    acc[0].x += v0.x; acc[0].y += v0.y; acc[0].z += v0.z; acc[0].w += v0.w;
    acc[1].x += v1.x; acc[1].y += v1.y; acc[1].z += v1.z; acc[1].w += v1.w;
    acc[2].x += v2.x; acc[2].y += v2.y; acc[2].z += v2.z; acc[2].w += v2.w;
    acc[3].x += v3.x; acc[3].y += v3.y; acc[3].z += v3.z; acc[3].w += v3.w;
    acc[4].x += v4.x; acc[4].y += v4.y; acc[4].z += v4.z; acc[4].w += v4.w;
    acc[5].x += v5.x; acc[5].y += v5.y; acc[5].z += v5.z; acc[5].w += v5.w;
    acc[6].x += v6.x; acc[6].y += v6.y; acc[6].z += v6.z; acc[6].w += v6.w;
    acc[7].x += v7.x; acc[7].y += v7.y; acc[7].z += v7.z; acc[7].w += v7.w;
  }
  if (e + 4 <= end) {
    int4 ia = *(const int4*)&csr_src[e];
    float4 v0 = Trow[(size_t)ia.x * LPN + lane];
    float4 v1 = Trow[(size_t)ia.y * LPN + lane];
    float4 v2 = Trow[(size_t)ia.z * LPN + lane];
    float4 v3 = Trow[(size_t)ia.w * LPN + lane];
    acc[0].x += v0.x; acc[0].y += v0.y; acc[0].z += v0.z; acc[0].w += v0.w;
    acc[1].x += v1.x; acc[1].y += v1.y; acc[1].z += v1.z; acc[1].w += v1.w;
    acc[2].x += v2.x; acc[2].y += v2.y; acc[2].z += v2.z; acc[2].w += v2.w;
    acc[3].x += v3.x; acc[3].y += v3.y; acc[3].z += v3.z; acc[3].w += v3.w;
    e += 4;
  }
  for (; e < end; ++e) {
    float4 v = Trow[(size_t)csr_src[e] * LPN + lane];
    acc[0].x += v.x; acc[0].y += v.y; acc[0].z += v.z; acc[0].w += v.w;
  }

  float4 s;
  s.x = ((acc[0].x + acc[1].x) + (acc[2].x + acc[3].x)) + ((acc[4].x + acc[5].x) + (acc[6].x + acc[7].x));
  s.y = ((acc[0].y + acc[1].y) + (acc[2].y + acc[3].y)) + ((acc[4].y + acc[5].y) + (acc[6].y + acc[7].y));
  s.z = ((acc[0].z + acc[1].z) + (acc[2].z + acc[3].z)) + ((acc[4].z + acc[5].z) + (acc[6].z + acc[7].z));
  s.w = ((acc[0].w + acc[1].w) + (acc[2].w + acc[3].w)) + ((acc[4].w + acc[5].w) + (acc[6].w + acc[7].w));

  float4 bv = *(const float4*)&bias[4 * lane];
  float4 h;
  h.x = fmaf(dn, s.x, bv.x);
  h.y = fmaf(dn, s.y, bv.y);
  h.z = fmaf(dn, s.z, bv.z);
  h.w = fmaf(dn, s.w, bv.w);
  if (RELU) {
    h.x = fmaxf(h.x, 0.f); h.y = fmaxf(h.y, 0.f);
    h.z = fmaxf(h.z, 0.f); h.w = fmaxf(h.w, 0.f);
  }
  ((float4*)H)[(size_t)node * LPN + lane] = h;

  if (FUSE_OUT) {  // C==64, LPN==16
    int k0 = 4 * lane;
    float p0 = h.x * Wout[(k0 + 0) * 2 + 0] + h.y * Wout[(k0 + 1) * 2 + 0] +
               h.z * Wout[(k0 + 2) * 2 + 0] + h.w * Wout[(k0 + 3) * 2 + 0];
    float p1 = h.x * Wout[(k0 + 0) * 2 + 1] + h.y * Wout[(k0 + 1) * 2 + 1] +
               h.z * Wout[(k0 + 2) * 2 + 1] + h.w * Wout[(k0 + 3) * 2 + 1];
#pragma unroll
    for (int off = 8; off >= 1; off >>= 1) {
      p0 += __shfl_xor(p0, off, 16);
      p1 += __shfl_xor(p1, off, 16);
    }
    if (lane == 0) {
      Out[(size_t)node * 2 + 0] = p0 + bout[0];
      Out[(size_t)node * 2 + 1] = p1 + bout[1];
    }
  }
}

extern "C" void kernel_launch(void* const* d_in, const int* in_sizes, int n_in,
                              void* d_out, int out_size, void* d_ws, size_t ws_size,
                              hipStream_t stream) {
  const float* x    = (const float*)d_in[0];
  const int*   ei   = (const int*)d_in[1];
  const float* W1   = (const float*)d_in[2];
  const float* b1   = (const float*)d_in[3];
  const float* W2   = (const float*)d_in[4];
  const float* b2   = (const float*)d_in[5];
  const float* W3   = (const float*)d_in[6];
  const float* b3   = (const float*)d_in[7];
  const float* Wout = (const float*)d_in[8];
  const float* bout = (const float*)d_in[9];

  const int n = NN, E = NE;
  const int* srcp = ei;
  const int* dstp = ei + E;

  char* ws = (char*)d_ws;
  int*   cnt     = (int*)(ws + 0);
  int*   cursor  = (int*)(ws + 400000);
  int*   row_ptr = (int*)(ws + 800000);
  float* dinv    = (float*)(ws + 1200128);
  int*   csr_src = (int*)(ws + 1600128);   // 16B-aligned
  float* bufA    = (float*)(ws + 14400128);
  float* bufB    = (float*)(ws + 65600128);

  float* outp = (float*)d_out;
  float* hemb = (float*)d_out + 2 * n;

  hipMemsetAsync(cnt, 0, n * sizeof(int), stream);
  hipMemsetAsync(cursor, 0, n * sizeof(int), stream);

  count_kernel<<<(E + 255) / 256, 256, 0, stream>>>(dstp, cnt, E);
  dinv_kernel<<<(n + 255) / 256, 256, 0, stream>>>(cnt, dinv, n);
  scan_kernel<<<1, 1024, 0, stream>>>(cnt, row_ptr, n);
  fill_kernel<<<(E + 255) / 256, 256, 0, stream>>>(srcp, dstp, row_ptr, cursor, csr_src, E);

  gemm_kernel<128><<<dim3((n + 127) / 128, 2), 512, 0, stream>>>(x, W1, dinv, bufA, n);
  agg_kernel<32, true, false><<<(n * 32 + 255) / 256, 256, 0, stream>>>(
      bufA, row_ptr, csr_src, dinv, b1, bufB, nullptr, nullptr, nullptr, n);

  gemm_kernel<128><<<dim3((n + 127) / 128, 2), 512, 0, stream>>>(bufB, W2, dinv, bufA, n);
  agg_kernel<32, true, false><<<(n * 32 + 255) / 256, 256, 0, stream>>>(
      bufA, row_ptr, csr_src, dinv, b2, bufB, nullptr, nullptr, nullptr, n);

  gemm_kernel<64><<<dim3((n + 127) / 128, 1), 512, 0, stream>>>(bufB, W3, dinv, bufA, n);
  agg_kernel<16, false, true><<<(n * 16 + 255) / 256, 256, 0, stream>>>(
      bufA, row_ptr, csr_src, dinv, b3, hemb, Wout, bout, outp, n);
}